// Round 3
// baseline (340.808 us; speedup 1.0000x reference)
//
#include <hip/hip_runtime.h>
#include <stdint.h>

#define B_SZ 1024
#define NO   16
#define CI   256
#define CO   256
#define BK   64
#define LDA  72      // padded LDS row length (shorts): 144B -> 4-bank rotation, b128 conflict-free
#define MAXG 12      // max groups per M (L=3: 11)
#define MAXE 48      // max entries per M (L=3: 39)

typedef unsigned short u16;
typedef __attribute__((ext_vector_type(8))) short short8;
typedef __attribute__((ext_vector_type(4))) float f32x4;
typedef __attribute__((ext_vector_type(4))) unsigned short u16x4;
typedef __attribute__((ext_vector_type(8))) unsigned short u16x8;

__device__ __forceinline__ u16 f2bf(float f) {
  union { float f; uint32_t u; } v; v.f = f;
  uint32_t u = v.u;
  return (u16)((u + 0x7FFFu + ((u >> 16) & 1u)) >> 16);   // RNE, finite inputs
}

__device__ __forceinline__ f32x4 mfma_16x16x32_bf16(short8 a, short8 b, f32x4 c) {
  // inline asm: immune to builtin operand-type (short8 vs __bf16x8) signature drift
  asm volatile("v_mfma_f32_16x16x32_bf16 %0, %1, %2, %0" : "+v"(c) : "v"(a), "v"(b));
  return c;
}

// coef[e][b] = CG[e] * sh[b, M2[e]]
extern "C" __global__ void coef_kernel(const float* __restrict__ CG,
                                       const float* __restrict__ sh,
                                       const int* __restrict__ M2,
                                       float* __restrict__ coef, int nnz) {
  int idx = blockIdx.x * 256 + threadIdx.x;
  if (idx >= nnz * B_SZ) return;
  int e = idx >> 10, b = idx & (B_SZ - 1);
  coef[idx] = CG[e] * sh[b * NO + M2[e]];
}

// wbf[w][o][i] = bf16(weight[w][i][o])  (pre-transposed so B-tile staging is k-contiguous)
extern "C" __global__ void wconv_kernel(const float* __restrict__ w,
                                        u16* __restrict__ wbf, int nthreads) {
  int t = blockIdx.x * 256 + threadIdx.x;
  if (t >= nthreads) return;
  int wi  = t >> 13;            // 8192 threads per 256x256 matrix
  int rem = t & 8191;
  int i8  = (rem & 31) * 8;     // 8 contiguous i per thread -> coalesced 16B writes
  int o   = rem >> 5;
  const float* src = w + (size_t)wi * (CI * CO);
  u16x8 pk;
#pragma unroll
  for (int j = 0; j < 8; ++j) pk[j] = f2bf(src[(size_t)(i8 + j) * CO + o]);
  *(u16x8*)(wbf + (size_t)wi * (CI * CO) + (size_t)o * CI + i8) = pk;
}

extern "C" __global__ void __launch_bounds__(256, 2)
so3_main(const float* __restrict__ x,
         const float* __restrict__ coef,
         const u16* __restrict__ wbf,
         const int* __restrict__ M1,
         const int* __restrict__ seg1,
         const int* __restrict__ lind,
         const int* __restrict__ seg2,
         float* __restrict__ out,
         int G, int nnz) {
  __shared__ u16 As[128 * LDA];
  __shared__ u16 Bs[128 * LDA];
  __shared__ float coefs[MAXE][128];
  __shared__ int s_meta[4];                 // gstart, gend, e0, e1
  __shared__ int s_estart[MAXG], s_eend[MAXG], s_wind[MAXG], s_m1[MAXE];

  const int tid = threadIdx.x;
  const int bid = blockIdx.x;
  const int b0  = (bid & 7) * 128;          // XCD = bid%8 = b-tile -> x slab (2MB) L2-resident
  const int M   = (bid >> 3) & 15;
  const int co0 = (bid >> 7) * 128;

  if (tid == 0) { s_meta[0] = 1 << 30; s_meta[1] = 0; s_meta[2] = 1 << 30; s_meta[3] = 0; }
  if (tid < MAXG) { s_estart[tid] = 1 << 30; s_eend[tid] = 0; }
  __syncthreads();
  for (int g = tid; g < G; g += 256)
    if (seg2[g] == M) { atomicMin(&s_meta[0], g); atomicMax(&s_meta[1], g + 1); }
  __syncthreads();
  const int gstart = s_meta[0];
  const int ng = s_meta[1] - gstart;        // groups for this M are contiguous by construction
  for (int e = tid; e < nnz; e += 256) {
    int g = seg1[e] - gstart;
    if (g >= 0 && g < ng) {
      atomicMin(&s_meta[2], e); atomicMax(&s_meta[3], e + 1);
      atomicMin(&s_estart[g], e); atomicMax(&s_eend[g], e + 1);
    }
  }
  __syncthreads();
  const int e0 = s_meta[2];
  const int ne = s_meta[3] - e0;            // <= 39 for L=3
  for (int i = tid; i < ng; i += 256) s_wind[i] = lind[gstart + i];
  for (int i = tid; i < ne; i += 256) s_m1[i] = M1[e0 + i];
  for (int idx = tid; idx < ne * 128; idx += 256) {
    int el = idx >> 7, r = idx & 127;
    coefs[el][r] = coef[(size_t)(e0 + el) * B_SZ + b0 + r];
  }
  __syncthreads();

  const int lane = tid & 63;
  const int wave = tid >> 6;
  const int wm = wave & 1, wn = wave >> 1;  // 2x2 waves over 128x128
  const int lrow = lane & 15, lq = lane >> 4;

  f32x4 acc[4][4];
#pragma unroll
  for (int i = 0; i < 4; ++i)
#pragma unroll
    for (int j = 0; j < 4; ++j) acc[i][j] = (f32x4){0.f, 0.f, 0.f, 0.f};

  const int ac  = (tid & 15) * 4;           // A staging: col group
  const int ar0 = (tid >> 4) * 8;           // A staging: row group

  for (int gl = 0; gl < ng; ++gl) {
    const int ea = s_estart[gl] - e0;
    const int eb = s_eend[gl] - e0;
    const u16* wb = wbf + (size_t)s_wind[gl] * (CI * CO) + (size_t)co0 * CI;
#pragma unroll 1
    for (int kk = 0; kk < CI; kk += BK) {
      // ---- A stage: inter[b0:b0+128, gl, kk:kk+64] -> bf16 LDS ----
#pragma unroll
      for (int r8 = 0; r8 < 8; ++r8) {
        int r = ar0 + r8;
        const float* xrow = x + (size_t)(b0 + r) * (NO * CI) + kk + ac;
        float4 a = make_float4(0.f, 0.f, 0.f, 0.f);
        for (int el = ea; el < eb; ++el) {
          float cf = coefs[el][r];
          float4 xv = *(const float4*)(xrow + s_m1[el] * CI);
          a.x = fmaf(cf, xv.x, a.x); a.y = fmaf(cf, xv.y, a.y);
          a.z = fmaf(cf, xv.z, a.z); a.w = fmaf(cf, xv.w, a.w);
        }
        u16x4 pk; pk[0] = f2bf(a.x); pk[1] = f2bf(a.y); pk[2] = f2bf(a.z); pk[3] = f2bf(a.w);
        *(u16x4*)&As[r * LDA + ac] = pk;
      }
      // ---- B stage: wbf[w][co0+o][kk+i] -> Bs[o][i] (both k-contiguous, 16B ops) ----
#pragma unroll
      for (int rr = 0; rr < 4; ++rr) {
        int idx = tid + rr * 256;
        int o = idx >> 3, ic = (idx & 7) * 8;
        *(u16x8*)&Bs[o * LDA + ic] = *(const u16x8*)(wb + (size_t)o * CI + kk + ic);
      }
      __syncthreads();
      // ---- MFMA: 2 k-substeps x 4x4 fragments ----
#pragma unroll
      for (int ks = 0; ks < 2; ++ks) {
        short8 af[4], bfr[4];
#pragma unroll
        for (int mf = 0; mf < 4; ++mf)
          af[mf] = *(const short8*)&As[(wm * 64 + mf * 16 + lrow) * LDA + ks * 32 + lq * 8];
#pragma unroll
        for (int nf = 0; nf < 4; ++nf)
          bfr[nf] = *(const short8*)&Bs[(wn * 64 + nf * 16 + lrow) * LDA + ks * 32 + lq * 8];
#pragma unroll
        for (int mf = 0; mf < 4; ++mf)
#pragma unroll
          for (int nf = 0; nf < 4; ++nf)
            acc[mf][nf] = mfma_16x16x32_bf16(af[mf], bfr[nf], acc[mf][nf]);
      }
      __syncthreads();
    }
  }

  // ---- epilogue: C layout col=lane&15, row=(lane>>4)*4+reg ----
#pragma unroll
  for (int mf = 0; mf < 4; ++mf) {
    int brow = b0 + wm * 64 + mf * 16 + lq * 4;
#pragma unroll
    for (int nf = 0; nf < 4; ++nf) {
      int o = co0 + wn * 64 + nf * 16 + lrow;
#pragma unroll
      for (int rg = 0; rg < 4; ++rg)
        out[(size_t)(brow + rg) * (NO * CO) + (size_t)M * CO + o] = acc[mf][nf][rg];
    }
  }
}

extern "C" void kernel_launch(void* const* d_in, const int* in_sizes, int n_in,
                              void* d_out, int out_size, void* d_ws, size_t ws_size,
                              hipStream_t stream) {
  const float* x   = (const float*)d_in[0];
  const float* sh  = (const float*)d_in[1];
  const float* wgt = (const float*)d_in[2];
  const float* CG  = (const float*)d_in[3];
  const int* M1    = (const int*)d_in[4];
  const int* M2    = (const int*)d_in[5];
  const int* seg1  = (const int*)d_in[6];
  const int* lind  = (const int*)d_in[7];
  const int* seg2  = (const int*)d_in[8];
  float* out       = (float*)d_out;

  const int nnz = in_sizes[3];
  const int G   = in_sizes[7];
  const int n_w = in_sizes[2] / (CI * CO);

  float* coef = (float*)d_ws;
  size_t coef_bytes = (size_t)nnz * B_SZ * sizeof(float);
  u16* wbf = (u16*)((char*)d_ws + ((coef_bytes + 255) & ~(size_t)255));

  int cthreads = nnz * B_SZ;
  coef_kernel<<<dim3((cthreads + 255) / 256), dim3(256), 0, stream>>>(CG, sh, M2, coef, nnz);
  int wthreads = n_w * 8192;
  wconv_kernel<<<dim3((wthreads + 255) / 256), dim3(256), 0, stream>>>(wgt, wbf, wthreads);
  so3_main<<<dim3(256), dim3(256), 0, stream>>>(x, coef, wbf, M1, seg1, lind, seg2, out, G, nnz);
}

// Round 4
// 192.002 us; speedup vs baseline: 1.7750x; 1.7750x over previous
//
#include <hip/hip_runtime.h>
#include <stdint.h>

#define B_SZ 1024
#define NO   16
#define CI   256
#define CO   256
#define BK   64
#define BM   32      // b-rows per block (small tile -> 1024 blocks -> ~50% occupancy)
#define LDA  72      // padded LDS row length (shorts): 144B -> 4-bank rotation
#define MAXG 12      // max groups per M (L=3: 11)
#define MAXE 48      // max entries per M (L=3: 39)

typedef unsigned short u16;
typedef __attribute__((ext_vector_type(8))) short short8;
typedef __attribute__((ext_vector_type(4))) float f32x4;
typedef __attribute__((ext_vector_type(4))) unsigned short u16x4;
typedef __attribute__((ext_vector_type(8))) unsigned short u16x8;

__device__ __forceinline__ u16 f2bf(float f) {
  union { float f; uint32_t u; } v; v.f = f;
  uint32_t u = v.u;
  return (u16)((u + 0x7FFFu + ((u >> 16) & 1u)) >> 16);   // RNE, finite inputs
}

__device__ __forceinline__ f32x4 mfma_16x16x32_bf16(short8 a, short8 b, f32x4 c) {
  asm volatile("v_mfma_f32_16x16x32_bf16 %0, %1, %2, %0" : "+v"(c) : "v"(a), "v"(b));
  return c;
}

// wbf[w][o][i] = bf16(weight[w][i][o])  (pre-transposed so B-tile staging is k-contiguous)
extern "C" __global__ void wconv_kernel(const float* __restrict__ w,
                                        u16* __restrict__ wbf, int nthreads) {
  int t = blockIdx.x * 256 + threadIdx.x;
  if (t >= nthreads) return;
  int wi  = t >> 13;            // 8192 threads per 256x256 matrix
  int rem = t & 8191;
  int i8  = (rem & 31) * 8;     // 8 contiguous i per thread
  int o   = rem >> 5;
  const float* src = w + (size_t)wi * (CI * CO);
  u16x8 pk;
#pragma unroll
  for (int j = 0; j < 8; ++j) pk[j] = f2bf(src[(size_t)(i8 + j) * CO + o]);
  *(u16x8*)(wbf + (size_t)wi * (CI * CO) + (size_t)o * CI + i8) = pk;
}

extern "C" __global__ void __launch_bounds__(256, 4)
so3_main(const float* __restrict__ x,
         const float* __restrict__ sh,
         const float* __restrict__ CG,
         const u16* __restrict__ wbf,
         const int* __restrict__ M1,
         const int* __restrict__ M2,
         const int* __restrict__ seg1,
         const int* __restrict__ lind,
         const int* __restrict__ seg2,
         float* __restrict__ out,
         int G, int nnz) {
  __shared__ u16 As[BM * LDA];              // 4.6 KB
  __shared__ u16 Bs[128 * LDA];             // 18.4 KB
  __shared__ float coefs[MAXE][BM];         // 6.1 KB
  __shared__ int s_meta[4];                 // gstart, gend, e0, e1
  __shared__ int s_estart[MAXG], s_eend[MAXG], s_wind[MAXG], s_m1[MAXE];

  const int tid = threadIdx.x;
  const int bid = blockIdx.x;
  const int b0  = (bid & 31) * BM;          // XCD = bid%8 -> btile%8 class -> x slab L2-resident
  const int M   = (bid >> 5) & 15;
  const int co0 = (bid >> 9) * 128;

  if (tid == 0) { s_meta[0] = 1 << 30; s_meta[1] = 0; s_meta[2] = 1 << 30; s_meta[3] = 0; }
  if (tid < MAXG) { s_estart[tid] = 1 << 30; s_eend[tid] = 0; }
  __syncthreads();
  for (int g = tid; g < G; g += 256)
    if (seg2[g] == M) { atomicMin(&s_meta[0], g); atomicMax(&s_meta[1], g + 1); }
  __syncthreads();
  const int gstart = s_meta[0];
  const int ng = s_meta[1] - gstart;        // groups for this M are contiguous by construction
  for (int e = tid; e < nnz; e += 256) {
    int g = seg1[e] - gstart;
    if (g >= 0 && g < ng) {
      atomicMin(&s_meta[2], e); atomicMax(&s_meta[3], e + 1);
      atomicMin(&s_estart[g], e); atomicMax(&s_eend[g], e + 1);
    }
  }
  __syncthreads();
  const int e0 = s_meta[2];
  const int ne = s_meta[3] - e0;            // <= 39 for L=3
  for (int i = tid; i < ng; i += 256) s_wind[i] = lind[gstart + i];
  for (int i = tid; i < ne; i += 256) s_m1[i] = M1[e0 + i];
  // coef fused in: coefs[el][r] = CG[e]*sh[b0+r, M2[e]]  (sh 64KB, CG/M2 tiny -> L2-hot)
  for (int idx = tid; idx < ne * BM; idx += 256) {
    int el = idx / BM, r = idx & (BM - 1);
    int e = e0 + el;
    coefs[el][r] = CG[e] * sh[(size_t)(b0 + r) * NO + M2[e]];
  }
  __syncthreads();

  const int lane = tid & 63;
  const int wave = tid >> 6;
  const int wn = wave;                      // 4 waves split 128 cols into 32-col strips
  const int lrow = lane & 15, lq = lane >> 4;

  f32x4 acc[2][2];
#pragma unroll
  for (int i = 0; i < 2; ++i)
#pragma unroll
    for (int j = 0; j < 2; ++j) acc[i][j] = (f32x4){0.f, 0.f, 0.f, 0.f};

  const int ac  = (tid & 15) * 4;           // A staging: col group (float4 of k)
  const int ar0 = (tid >> 4) * 2;           // A staging: 2 rows per thread

  for (int gl = 0; gl < ng; ++gl) {
    const int ea = s_estart[gl] - e0;
    const int eb = s_eend[gl] - e0;
    const u16* wb = wbf + (size_t)s_wind[gl] * (CI * CO) + (size_t)co0 * CI;
#pragma unroll 1
    for (int kk = 0; kk < CI; kk += BK) {
      // ---- A stage: inter[b0:b0+32, gl, kk:kk+64] -> bf16 LDS ----
#pragma unroll
      for (int r2 = 0; r2 < 2; ++r2) {
        int r = ar0 + r2;
        const float* xrow = x + (size_t)(b0 + r) * (NO * CI) + kk + ac;
        float4 a = make_float4(0.f, 0.f, 0.f, 0.f);
        for (int el = ea; el < eb; ++el) {
          float cf = coefs[el][r];
          float4 xv = *(const float4*)(xrow + s_m1[el] * CI);
          a.x = fmaf(cf, xv.x, a.x); a.y = fmaf(cf, xv.y, a.y);
          a.z = fmaf(cf, xv.z, a.z); a.w = fmaf(cf, xv.w, a.w);
        }
        u16x4 pk; pk[0] = f2bf(a.x); pk[1] = f2bf(a.y); pk[2] = f2bf(a.z); pk[3] = f2bf(a.w);
        *(u16x4*)&As[r * LDA + ac] = pk;
      }
      // ---- B stage: wbf[w][co0+o][kk+i] -> Bs[o][i] (k-contiguous 16B ops) ----
#pragma unroll
      for (int rr = 0; rr < 4; ++rr) {
        int idx = tid + rr * 256;
        int o = idx >> 3, ic = (idx & 7) * 8;
        *(u16x8*)&Bs[o * LDA + ic] = *(const u16x8*)(wb + (size_t)o * CI + kk + ic);
      }
      __syncthreads();
      // ---- MFMA: 2 k-substeps x 2x2 fragments per wave ----
#pragma unroll
      for (int ks = 0; ks < 2; ++ks) {
        short8 af[2], bfr[2];
#pragma unroll
        for (int mf = 0; mf < 2; ++mf)
          af[mf] = *(const short8*)&As[(mf * 16 + lrow) * LDA + ks * 32 + lq * 8];
#pragma unroll
        for (int nf = 0; nf < 2; ++nf)
          bfr[nf] = *(const short8*)&Bs[(wn * 32 + nf * 16 + lrow) * LDA + ks * 32 + lq * 8];
#pragma unroll
        for (int mf = 0; mf < 2; ++mf)
#pragma unroll
          for (int nf = 0; nf < 2; ++nf)
            acc[mf][nf] = mfma_16x16x32_bf16(af[mf], bfr[nf], acc[mf][nf]);
      }
      __syncthreads();
    }
  }

  // ---- epilogue: C layout col=lane&15, row=(lane>>4)*4+reg ----
#pragma unroll
  for (int mf = 0; mf < 2; ++mf) {
    int brow = b0 + mf * 16 + lq * 4;
#pragma unroll
    for (int nf = 0; nf < 2; ++nf) {
      int o = co0 + wn * 32 + nf * 16 + lrow;
#pragma unroll
      for (int rg = 0; rg < 4; ++rg)
        out[(size_t)(brow + rg) * (NO * CO) + (size_t)M * CO + o] = acc[mf][nf][rg];
    }
  }
}

extern "C" void kernel_launch(void* const* d_in, const int* in_sizes, int n_in,
                              void* d_out, int out_size, void* d_ws, size_t ws_size,
                              hipStream_t stream) {
  const float* x   = (const float*)d_in[0];
  const float* sh  = (const float*)d_in[1];
  const float* wgt = (const float*)d_in[2];
  const float* CG  = (const float*)d_in[3];
  const int* M1    = (const int*)d_in[4];
  const int* M2    = (const int*)d_in[5];
  const int* seg1  = (const int*)d_in[6];
  const int* lind  = (const int*)d_in[7];
  const int* seg2  = (const int*)d_in[8];
  float* out       = (float*)d_out;

  const int nnz = in_sizes[3];
  const int G   = in_sizes[7];
  const int n_w = in_sizes[2] / (CI * CO);

  u16* wbf = (u16*)d_ws;

  int wthreads = n_w * 8192;
  wconv_kernel<<<dim3((wthreads + 255) / 256), dim3(256), 0, stream>>>(wgt, wbf, wthreads);
  so3_main<<<dim3(1024), dim3(256), 0, stream>>>(x, sh, CG, wbf, M1, M2, seg1, lind, seg2,
                                                 out, G, nnz);
}

// Round 6
// 173.139 us; speedup vs baseline: 1.9684x; 1.1089x over previous
//
#include <hip/hip_runtime.h>
#include <stdint.h>

#define B_SZ 1024
#define NO   16
#define CI   256
#define CO   256
#define BK   64
#define BM   32      // b-rows per block
#define LDA  72      // padded LDS row (shorts): 144B stride -> 4-bank rotation, b128 conflict-free
#define MAXG 12      // max groups per M (L=3: 11)
#define MAXE 48      // max entries per M (L=3: 39)
#define WP   76      // wconv LDS pad (shorts)

typedef unsigned short u16;
typedef __attribute__((ext_vector_type(8))) short short8;
typedef __attribute__((ext_vector_type(4))) float f32x4;
typedef __attribute__((ext_vector_type(4))) unsigned short u16x4;
typedef __attribute__((ext_vector_type(8))) unsigned short u16x8;

__device__ __forceinline__ u16 f2bf(float f) {
  union { float f; uint32_t u; } v; v.f = f;
  uint32_t u = v.u;
  return (u16)((u + 0x7FFFu + ((u >> 16) & 1u)) >> 16);   // RNE, finite inputs
}
__device__ __forceinline__ float bf2f(u16 h) {
  union { float f; uint32_t u; } v; v.u = ((uint32_t)h) << 16; return v.f;
}

__device__ __forceinline__ f32x4 mfma_16x16x32_bf16(short8 a, short8 b, f32x4 c) {
  asm volatile("v_mfma_f32_16x16x32_bf16 %0, %1, %2, %0" : "+v"(c) : "v"(a), "v"(b));
  return c;
}

// xbf[b][order][k] = bf16(x[...]), flat copy-convert, 8 elems/thread
extern "C" __global__ void xconv_kernel(const float* __restrict__ x,
                                        u16* __restrict__ xbf, int n8) {
  int t = blockIdx.x * 256 + threadIdx.x;
  if (t >= n8) return;
  const float* s = x + (size_t)t * 8;
  float4 a = ((const float4*)s)[0];
  float4 b = ((const float4*)s)[1];
  u16x8 pk;
  pk[0] = f2bf(a.x); pk[1] = f2bf(a.y); pk[2] = f2bf(a.z); pk[3] = f2bf(a.w);
  pk[4] = f2bf(b.x); pk[5] = f2bf(b.y); pk[6] = f2bf(b.z); pk[7] = f2bf(b.w);
  *(u16x8*)(xbf + (size_t)t * 8) = pk;
}

// wbf[w][o][i] = bf16(weight[w][i][o]) via 64x64 LDS-transpose tiles (both sides coalesced)
extern "C" __global__ void wconv_kernel(const float* __restrict__ w,
                                        u16* __restrict__ wbf) {
  __shared__ u16 t_lds[64 * WP];
  const int tid = threadIdx.x;
  const int bid = blockIdx.x;
  const int wi = bid >> 4;
  const int i0 = ((bid >> 2) & 3) * 64;
  const int o0 = (bid & 3) * 64;
  const float* src = w + (size_t)wi * (CI * CO);
  u16* dst = wbf + (size_t)wi * (CI * CO);
#pragma unroll
  for (int p = 0; p < 4; ++p) {
    int idx = p * 256 + tid;
    int i = idx >> 4, oq = (idx & 15) * 4;       // lanes: contiguous 256B along o
    float4 v = *(const float4*)(src + (size_t)(i0 + i) * CO + o0 + oq);
    t_lds[(oq + 0) * WP + i] = f2bf(v.x);
    t_lds[(oq + 1) * WP + i] = f2bf(v.y);
    t_lds[(oq + 2) * WP + i] = f2bf(v.z);
    t_lds[(oq + 3) * WP + i] = f2bf(v.w);
  }
  __syncthreads();
#pragma unroll
  for (int p = 0; p < 4; ++p) {
    int idx = p * 256 + tid;
    int o = idx >> 4, iq = (idx & 15) * 4;       // lanes: contiguous 128B along i
    u16x4 v;
    v[0] = t_lds[o * WP + iq + 0]; v[1] = t_lds[o * WP + iq + 1];
    v[2] = t_lds[o * WP + iq + 2]; v[3] = t_lds[o * WP + iq + 3];
    *(u16x4*)(dst + (size_t)(o0 + o) * CI + i0 + iq) = v;
  }
}

extern "C" __global__ void __launch_bounds__(256, 4)
so3_main(const u16* __restrict__ xbf,
         const float* __restrict__ sh,
         const float* __restrict__ CG,
         const u16* __restrict__ wbf,
         const int* __restrict__ M1,
         const int* __restrict__ M2,
         const int* __restrict__ seg1,
         const int* __restrict__ lind,
         const int* __restrict__ seg2,
         float* __restrict__ out,
         int G, int nnz) {
  __shared__ u16 As[BM * LDA];              // 4.6 KB
  __shared__ u16 Bs[128 * LDA];             // 18.4 KB
  __shared__ float coefs[MAXE][BM];         // 6.1 KB
  __shared__ int s_meta[4];
  __shared__ int s_estart[MAXG], s_eend[MAXG], s_wind[MAXG], s_m1[MAXE];

  const int tid = threadIdx.x;
  const int bid = blockIdx.x;
  const int b0  = (bid & 31) * BM;          // XCD = bid%8 -> x slab L2-resident
  const int M   = (bid >> 5) & 15;
  const int co0 = (bid >> 9) * 128;

  if (tid == 0) { s_meta[0] = 1 << 30; s_meta[1] = 0; s_meta[2] = 1 << 30; s_meta[3] = 0; }
  if (tid < MAXG) { s_estart[tid] = 1 << 30; s_eend[tid] = 0; }
  __syncthreads();
  for (int g = tid; g < G; g += 256)
    if (seg2[g] == M) { atomicMin(&s_meta[0], g); atomicMax(&s_meta[1], g + 1); }
  __syncthreads();
  const int gstart = s_meta[0];
  const int ng = s_meta[1] - gstart;        // groups for this M are contiguous
  for (int e = tid; e < nnz; e += 256) {
    int g = seg1[e] - gstart;
    if (g >= 0 && g < ng) {
      atomicMin(&s_meta[2], e); atomicMax(&s_meta[3], e + 1);
      atomicMin(&s_estart[g], e); atomicMax(&s_eend[g], e + 1);
    }
  }
  __syncthreads();
  const int e0 = s_meta[2];
  const int ne = s_meta[3] - e0;            // <= 39 for L=3
  for (int i = tid; i < ng; i += 256) s_wind[i] = lind[gstart + i];
  for (int i = tid; i < ne; i += 256) s_m1[i] = M1[e0 + i];
  for (int idx = tid; idx < ne * BM; idx += 256) {
    int el = idx / BM, r = idx & (BM - 1);
    int e = e0 + el;
    coefs[el][r] = CG[e] * sh[(size_t)(b0 + r) * NO + M2[e]];
  }
  __syncthreads();

  const int lane = tid & 63;
  const int wn = tid >> 6;                  // 4 waves: 32-col strips of BN=128
  const int lrow = lane & 15, lq = lane >> 4;
  const int ar = tid >> 3;                  // A-build: row 0..31
  const int ak = (tid & 7) * 8;             // A-build: k-octet (shorts)

  f32x4 acc[2][2];
#pragma unroll
  for (int i = 0; i < 2; ++i)
#pragma unroll
    for (int j = 0; j < 2; ++j) acc[i][j] = (f32x4){0.f, 0.f, 0.f, 0.f};

  const int T = ng * 4;
  u16x8 breg[4];
  {   // prefetch B(0): gl=0, kk=0
    const u16* wb = wbf + (size_t)s_wind[0] * (CI * CO) + (size_t)co0 * CI;
#pragma unroll
    for (int rr = 0; rr < 4; ++rr) {
      int idx = tid + rr * 256, o = idx >> 3, ic = (idx & 7) * 8;
      breg[rr] = *(const u16x8*)(wb + (size_t)o * CI + ic);
    }
  }

  for (int t = 0; t < T; ++t) {
    const int gl = t >> 2, kk = (t & 3) * BK;
    const int ea = s_estart[gl] - e0, eb = s_eend[gl] - e0;
    // ---- A build: inter[b0+ar, gl, kk+ak..+7] in fp32, pack bf16 -> LDS ----
    {
      const u16* xrow = xbf + (size_t)(b0 + ar) * (NO * CI) + kk + ak;
      float ax[8];
#pragma unroll
      for (int j = 0; j < 8; ++j) ax[j] = 0.f;
      for (int el = ea; el < eb; ++el) {
        float cf = coefs[el][ar];
        u16x8 xv = *(const u16x8*)(xrow + (size_t)s_m1[el] * CI);
#pragma unroll
        for (int j = 0; j < 8; ++j) ax[j] = fmaf(cf, bf2f(xv[j]), ax[j]);
      }
      u16x8 pk;
#pragma unroll
      for (int j = 0; j < 8; ++j) pk[j] = f2bf(ax[j]);
      *(u16x8*)&As[ar * LDA + ak] = pk;
    }
    // ---- B: write prefetched regs (phase t's tile) to LDS ----
#pragma unroll
    for (int rr = 0; rr < 4; ++rr) {
      int idx = tid + rr * 256, o = idx >> 3, ic = (idx & 7) * 8;
      *(u16x8*)&Bs[o * LDA + ic] = breg[rr];
    }
    // ---- issue next-phase B loads (latency hides under barrier+MFMA+next A-build) ----
    {
      int tn = (t + 1 < T) ? t + 1 : t;
      int gln = tn >> 2, kkn = (tn & 3) * BK;
      const u16* wbn = wbf + (size_t)s_wind[gln] * (CI * CO) + (size_t)co0 * CI + kkn;
#pragma unroll
      for (int rr = 0; rr < 4; ++rr) {
        int idx = tid + rr * 256, o = idx >> 3, ic = (idx & 7) * 8;
        breg[rr] = *(const u16x8*)(wbn + (size_t)o * CI + ic);
      }
    }
    __syncthreads();
    // ---- MFMA: 2 k-substeps x 2x2 fragments per wave ----
#pragma unroll
    for (int ks = 0; ks < 2; ++ks) {
      short8 af[2], bfr[2];
#pragma unroll
      for (int mf = 0; mf < 2; ++mf)
        af[mf] = *(const short8*)&As[(mf * 16 + lrow) * LDA + ks * 32 + lq * 8];
#pragma unroll
      for (int nf = 0; nf < 2; ++nf)
        bfr[nf] = *(const short8*)&Bs[(wn * 32 + nf * 16 + lrow) * LDA + ks * 32 + lq * 8];
#pragma unroll
      for (int mf = 0; mf < 2; ++mf)
#pragma unroll
        for (int nf = 0; nf < 2; ++nf)
          acc[mf][nf] = mfma_16x16x32_bf16(af[mf], bfr[nf], acc[mf][nf]);
    }
    __syncthreads();
  }

  // ---- epilogue: C layout col=lane&15, row=(lane>>4)*4+reg ----
#pragma unroll
  for (int mf = 0; mf < 2; ++mf) {
    int brow = b0 + mf * 16 + lq * 4;
#pragma unroll
    for (int nf = 0; nf < 2; ++nf) {
      int o = co0 + wn * 32 + nf * 16 + lrow;
#pragma unroll
      for (int rg = 0; rg < 4; ++rg)
        out[(size_t)(brow + rg) * (NO * CO) + (size_t)M * CO + o] = acc[mf][nf][rg];
    }
  }
}

extern "C" void kernel_launch(void* const* d_in, const int* in_sizes, int n_in,
                              void* d_out, int out_size, void* d_ws, size_t ws_size,
                              hipStream_t stream) {
  const float* x   = (const float*)d_in[0];
  const float* sh  = (const float*)d_in[1];
  const float* wgt = (const float*)d_in[2];
  const float* CG  = (const float*)d_in[3];
  const int* M1    = (const int*)d_in[4];
  const int* M2    = (const int*)d_in[5];
  const int* seg1  = (const int*)d_in[6];
  const int* lind  = (const int*)d_in[7];
  const int* seg2  = (const int*)d_in[8];
  float* out       = (float*)d_out;

  const int nnz = in_sizes[3];
  const int G   = in_sizes[7];
  const int n_w = in_sizes[2] / (CI * CO);

  u16* xbf = (u16*)d_ws;                                   // 8.39 MB
  u16* wbf = (u16*)((char*)d_ws + (size_t)B_SZ * NO * CI * 2);  // 4.46 MB

  int n8 = B_SZ * NO * CI / 8;
  xconv_kernel<<<dim3(n8 / 256), dim3(256), 0, stream>>>(x, xbf, n8);
  wconv_kernel<<<dim3(n_w * 16), dim3(256), 0, stream>>>(wgt, wbf);
  so3_main<<<dim3(1024), dim3(256), 0, stream>>>(xbf, sh, CG, wbf, M1, M2, seg1, lind, seg2,
                                                 out, G, nnz);
}